// Round 1
// baseline (724.117 us; speedup 1.0000x reference)
//
#include <hip/hip_runtime.h>
#include <hip/hip_bf16.h>

// Problem constants (static per reference)
constexpr int Bm   = 512;   // molecules
constexpr int Aa   = 128;   // atoms / molecule
constexpr int Ee   = 256;   // directed bonds / molecule
constexpr int Kk   = 6;     // incoming bonds gathered
constexpr int AFD  = 133;   // atom feature dim
constexpr int FD   = 147;   // 133 + 14 bond feature dim
constexpr int Hh   = 128;   // hidden
constexpr int CATD = 261;   // 133 + 128

// ---------------------------------------------------------------------------
// Shared GEMM core: C[64 x 128] tile, K processed in 64-wide chunks.
// Threads: 256.  hq = tid&31 owns cols {hq, hq+32, hq+64, hq+96};
//                rq = tid>>5 owns rows {rq*8 .. rq*8+7}.
// At layout: [r][f] stride 68 (16B-aligned rows, broadcast reads -> free)
// Wt layout: [f][h] stride 129 (staging writes + compute reads conflict-free)
// ---------------------------------------------------------------------------
__device__ __forceinline__ void gemm_core(const float* At, const float* Wt,
                                          int hq, int rq, float acc[8][4]) {
    for (int f4 = 0; f4 < 64; f4 += 4) {
        float4 a4[8];
#pragma unroll
        for (int j = 0; j < 8; ++j)
            a4[j] = *(const float4*)&At[(rq * 8 + j) * 68 + f4];
        float w[4][4];
#pragma unroll
        for (int t = 0; t < 4; ++t)
#pragma unroll
            for (int c = 0; c < 4; ++c)
                w[t][c] = Wt[(f4 + t) * 129 + hq + 32 * c];
#pragma unroll
        for (int j = 0; j < 8; ++j) {
            const float* af = reinterpret_cast<const float*>(&a4[j]);
#pragma unroll
            for (int t = 0; t < 4; ++t)
#pragma unroll
                for (int c = 0; c < 4; ++c)
                    acc[j][c] += af[t] * w[t][c];
        }
    }
}

// ---------------------------------------------------------------------------
// Kernel 1: inp = f_ini @ W_i^T ; msg = relu(inp)
// ---------------------------------------------------------------------------
__global__ __launch_bounds__(256) void k_wi(const float* __restrict__ fini,
                                            const float* __restrict__ Wi,
                                            float* __restrict__ inp,
                                            __hip_bfloat16* __restrict__ msg) {
    __shared__ float At[64 * 68];
    __shared__ float Wt[64 * 129];
    const int tid  = threadIdx.x;
    const int row0 = blockIdx.x * 64;
    const int hq = tid & 31, rq = tid >> 5;
    float acc[8][4] = {};

    for (int fb = 0; fb < FD; fb += 64) {
        for (int idx = tid; idx < 64 * 64; idx += 256) {
            int r = idx >> 6, f = idx & 63, ff = fb + f;
            At[r * 68 + f] = (ff < FD) ? fini[(size_t)(row0 + r) * FD + ff] : 0.f;
        }
        for (int idx = tid; idx < 128 * 64; idx += 256) {
            int h = idx >> 6, f = idx & 63, ff = fb + f;
            Wt[f * 129 + h] = (ff < FD) ? Wi[h * FD + ff] : 0.f;
        }
        __syncthreads();
        gemm_core(At, Wt, hq, rq, acc);
        __syncthreads();
    }
#pragma unroll
    for (int j = 0; j < 8; ++j) {
        int row = row0 + rq * 8 + j;
#pragma unroll
        for (int c = 0; c < 4; ++c) {
            int col = hq + 32 * c;
            float v = acc[j][c];
            inp[(size_t)row * Hh + col] = v;
            msg[(size_t)row * Hh + col] = __float2bfloat16(v > 0.f ? v : 0.f);
        }
    }
}

// ---------------------------------------------------------------------------
// Kernel 2 (x2): msgOut = relu(inp + gather_sum(msgIn, mapping) @ W_h^T)
// Gather fused into A-tile staging.
// ---------------------------------------------------------------------------
__global__ __launch_bounds__(256) void k_hop(const __hip_bfloat16* __restrict__ msgIn,
                                             const int* __restrict__ mapping,
                                             const float* __restrict__ Wh,
                                             const float* __restrict__ inp,
                                             __hip_bfloat16* __restrict__ msgOut) {
    __shared__ float At[64 * 68];
    __shared__ float Wt[64 * 129];
    const int tid  = threadIdx.x;
    const int row0 = blockIdx.x * 64;           // global bond-row
    const int bBase = (row0 >> 8) * Ee;         // molecule base row
    const int hq = tid & 31, rq = tid >> 5;
    float acc[8][4] = {};

    for (int fb = 0; fb < Hh; fb += 64) {
        for (int idx = tid; idx < 64 * 64; idx += 256) {
            int r = idx >> 6, f = idx & 63;
            int row = row0 + r;
            int ff = fb + f;
            const int* mp = &mapping[row * Kk];
            float s = 0.f;
#pragma unroll
            for (int k = 0; k < Kk; ++k) {
                int e = mp[k];
                s += __bfloat162float(msgIn[(size_t)(bBase + e) * Hh + ff]);
            }
            At[r * 68 + f] = s;
        }
        for (int idx = tid; idx < 128 * 64; idx += 256) {
            int h = idx >> 6, f = idx & 63, ff = fb + f;
            Wt[f * 129 + h] = Wh[h * Hh + ff];
        }
        __syncthreads();
        gemm_core(At, Wt, hq, rq, acc);
        __syncthreads();
    }
#pragma unroll
    for (int j = 0; j < 8; ++j) {
        int row = row0 + rq * 8 + j;
#pragma unroll
        for (int c = 0; c < 4; ++c) {
            int col = hq + 32 * c;
            float v = inp[(size_t)row * Hh + col] + acc[j][c];
            msgOut[(size_t)row * Hh + col] = __float2bfloat16(v > 0.f ? v : 0.f);
        }
    }
}

// ---------------------------------------------------------------------------
// Kernel 3: readout.  cat = [atom_feature, gather_sum(msg, a2ib)],
// atoms_h = relu(cat @ W_o^T + b_o), scattered to packed output rows.
// ---------------------------------------------------------------------------
__global__ __launch_bounds__(256) void k_read(const __hip_bfloat16* __restrict__ msg,
                                              const int* __restrict__ a2ib,
                                              const float* __restrict__ atomf,
                                              const float* __restrict__ Wo,
                                              const float* __restrict__ bo,
                                              const int* __restrict__ mol_lens,
                                              const int* __restrict__ pfx,
                                              float* __restrict__ out) {
    __shared__ float At[64 * 68];
    __shared__ float Wt[64 * 129];
    const int tid  = threadIdx.x;
    const int row0 = blockIdx.x * 64;           // global atom-row (b*128 + a)
    const int b    = row0 >> 7;
    const int bBase = b * Ee;
    const int hq = tid & 31, rq = tid >> 5;
    float acc[8][4] = {};

    for (int fb = 0; fb < CATD; fb += 64) {
        for (int idx = tid; idx < 64 * 64; idx += 256) {
            int r = idx >> 6, f = idx & 63;
            int row = row0 + r;
            int ff = fb + f;
            float v;
            if (ff < AFD) {
                v = atomf[(size_t)row * AFD + ff];
            } else if (ff < CATD) {
                int hh = ff - AFD;
                const int* mp = &a2ib[row * Kk];
                float s = 0.f;
#pragma unroll
                for (int k = 0; k < Kk; ++k) {
                    int e = mp[k];
                    s += __bfloat162float(msg[(size_t)(bBase + e) * Hh + hh]);
                }
                v = s;
            } else {
                v = 0.f;
            }
            At[r * 68 + f] = v;
        }
        for (int idx = tid; idx < 128 * 64; idx += 256) {
            int h = idx >> 6, f = idx & 63, ff = fb + f;
            Wt[f * 129 + h] = (ff < CATD) ? Wo[h * CATD + ff] : 0.f;
        }
        __syncthreads();
        gemm_core(At, Wt, hq, rq, acc);
        __syncthreads();
    }

    const int len  = mol_lens[b];
    const int base = pfx[b];
#pragma unroll
    for (int j = 0; j < 8; ++j) {
        int row = row0 + rq * 8 + j;
        int a   = row & (Aa - 1);
        if (a < len) {
#pragma unroll
            for (int c = 0; c < 4; ++c) {
                int col = hq + 32 * c;
                float v = acc[j][c] + bo[col];
                out[(size_t)(base + a) * Hh + col] = v > 0.f ? v : 0.f;
            }
        }
    }
}

// ---------------------------------------------------------------------------
// Prefix sum over mol_lens (exclusive) — single block Hillis-Steele.
// ---------------------------------------------------------------------------
__global__ __launch_bounds__(512) void k_scan(const int* __restrict__ ml,
                                              int* __restrict__ pfx) {
    __shared__ int s[512];
    int t = threadIdx.x;
    s[t] = ml[t];
    __syncthreads();
    for (int off = 1; off < 512; off <<= 1) {
        int v = (t >= off) ? s[t - off] : 0;
        __syncthreads();
        s[t] += v;
        __syncthreads();
    }
    pfx[t + 1] = s[t];
    if (t == 0) pfx[0] = 0;
}

__global__ __launch_bounds__(128) void k_cmask(const int* __restrict__ ml,
                                               float* __restrict__ cmask) {
    int b = blockIdx.x, t = threadIdx.x;
    cmask[b * Aa + t] = (t < ml[b]) ? 1.0f : 0.0f;
}

// ---------------------------------------------------------------------------
extern "C" void kernel_launch(void* const* d_in, const int* in_sizes, int n_in,
                              void* d_out, int out_size, void* d_ws, size_t ws_size,
                              hipStream_t stream) {
    const float* atom_feature = (const float*)d_in[0];
    const float* f_ini        = (const float*)d_in[1];
    const int*   a2ib         = (const int*)d_in[2];
    const int*   mapping      = (const int*)d_in[3];
    // d_in[4] = global_f (unused by reference)
    const int*   mol_lens     = (const int*)d_in[5];
    const float* Wi           = (const float*)d_in[6];
    const float* Wh           = (const float*)d_in[7];
    const float* Wo           = (const float*)d_in[8];
    const float* bo           = (const float*)d_in[9];
    float* out = (float*)d_out;

    // Workspace layout: inp fp32 (64 MB), msgA/msgB bf16 (32 MB each), pfx
    constexpr size_t NMSG = (size_t)Bm * Ee * Hh;   // 16,777,216
    float*          inp  = (float*)d_ws;
    __hip_bfloat16* msgA = (__hip_bfloat16*)(inp + NMSG);
    __hip_bfloat16* msgB = msgA + NMSG;
    int*            pfx  = (int*)(msgB + NMSG);

    float* cmask = out + ((size_t)out_size - (size_t)Bm * Aa);

    k_scan <<<1, 512, 0, stream>>>(mol_lens, pfx);
    k_cmask<<<Bm, 128, 0, stream>>>(mol_lens, cmask);
    k_wi   <<<(Bm * Ee) / 64, 256, 0, stream>>>(f_ini, Wi, inp, msgA);
    k_hop  <<<(Bm * Ee) / 64, 256, 0, stream>>>(msgA, mapping, Wh, inp, msgB);
    k_hop  <<<(Bm * Ee) / 64, 256, 0, stream>>>(msgB, mapping, Wh, inp, msgA);
    k_read <<<(Bm * Aa) / 64, 256, 0, stream>>>(msgA, a2ib, atom_feature, Wo, bo,
                                                mol_lens, pfx, out);
}

// Round 2
// 358.877 us; speedup vs baseline: 2.0177x; 2.0177x over previous
//
#include <hip/hip_runtime.h>
#include <hip/hip_bf16.h>

typedef unsigned int  uint;
typedef unsigned short ushort;
typedef short bf16x8 __attribute__((ext_vector_type(8)));
typedef float f32x4  __attribute__((ext_vector_type(4)));

// Problem constants
constexpr int Bm   = 512;   // molecules
constexpr int Aa   = 128;   // atoms / molecule
constexpr int Ee   = 256;   // directed bonds / molecule
constexpr int Kk   = 6;     // incoming gathered
constexpr int AFD  = 133;
constexpr int FD   = 147;   // 133+14
constexpr int Hh   = 128;
constexpr int CATD = 261;   // 133+128
constexpr int KWI  = 192;   // padded K for W_i GEMM
constexpr int KRD  = 320;   // padded K for W_o GEMM: [0,133) atomf, [133,192) zero, [192,320) m2a
constexpr int LDA  = 72;    // LDS row stride (bf16 elems): 64 + 8 pad -> 2-way max aliasing

// ---- bf16 helpers (manual RNE; bf16->f32 is a shift) -----------------------
__device__ __forceinline__ ushort f2b(float f) {
    uint u = __float_as_uint(f);
    u += 0x7FFFu + ((u >> 16) & 1u);
    return (ushort)(u >> 16);
}
__device__ __forceinline__ uint f2b2(float x, float y) {
    return (uint)f2b(x) | ((uint)f2b(y) << 16);
}
__device__ __forceinline__ float2 b2f2(uint p) {
    float2 r;
    r.x = __uint_as_float(p << 16);
    r.y = __uint_as_float(p & 0xFFFF0000u);
    return r;
}
__device__ __forceinline__ float b2f(ushort u) {
    return __uint_as_float(((uint)u) << 16);
}

// ---------------------------------------------------------------------------
// MFMA core: block computes 128 rows x 128 cols. 4 waves in 2x2:
// wave w: wr=w&1 (row half), wc=w>>1 (col half). Each wave: 4x4 16x16 tiles.
// A-frag: lane holds A[m=l15][k=quad*8+j]; B-frag: B[n=l15][k=quad*8+j]
// (B source = W[h][k] row-major, k contiguous). D: col=l15, row=quad*4+reg.
// One call consumes a K-chunk of 64 (2 k-steps of 32).
// ---------------------------------------------------------------------------
__device__ __forceinline__ void mfma_chunk(const ushort* At, const ushort* Bt,
                                           int wr, int wc, int l15, int quad,
                                           f32x4 acc[4][4]) {
#pragma unroll
    for (int ks = 0; ks < 2; ++ks) {
        const int ko = ks * 32 + quad * 8;
        bf16x8 af[4], bf[4];
#pragma unroll
        for (int i = 0; i < 4; ++i)
            af[i] = *(const bf16x8*)&At[(wr * 64 + i * 16 + l15) * LDA + ko];
#pragma unroll
        for (int j = 0; j < 4; ++j)
            bf[j] = *(const bf16x8*)&Bt[(wc * 64 + j * 16 + l15) * LDA + ko];
#pragma unroll
        for (int i = 0; i < 4; ++i)
#pragma unroll
            for (int j = 0; j < 4; ++j)
                acc[i][j] = __builtin_amdgcn_mfma_f32_16x16x32_bf16(
                    af[i], bf[j], acc[i][j], 0, 0, 0);
    }
}

// ---------------------------------------------------------------------------
// Prep: weights -> bf16 padded/remapped; atom features -> bf16 padded
// ---------------------------------------------------------------------------
__global__ __launch_bounds__(256) void k_prep_w(const float* __restrict__ Wi,
                                                const float* __restrict__ Wh,
                                                const float* __restrict__ Wo,
                                                ushort* __restrict__ Wi_b,
                                                ushort* __restrict__ Wh_b,
                                                ushort* __restrict__ Wo_b) {
    const int h = blockIdx.x, t = threadIdx.x;
    for (int c = t; c < KWI; c += 256)
        Wi_b[h * KWI + c] = f2b(c < FD ? Wi[h * FD + c] : 0.f);
    for (int c = t; c < Hh; c += 256)
        Wh_b[h * Hh + c] = f2b(Wh[h * Hh + c]);
    for (int c = t; c < KRD; c += 256) {
        float v = 0.f;
        if (c < AFD)       v = Wo[h * CATD + c];
        else if (c >= 192) v = Wo[h * CATD + AFD + (c - 192)];
        Wo_b[h * KRD + c] = f2b(v);
    }
}

__global__ __launch_bounds__(192) void k_prep_a(const float* __restrict__ atomf,
                                                ushort* __restrict__ atomf_b) {
    const int row = blockIdx.x, t = threadIdx.x;  // 65536 rows, 192 threads
    float v = (t < AFD) ? atomf[(size_t)row * AFD + t] : 0.f;
    atomf_b[(size_t)row * KWI + t] = f2b(v);
}

// ---------------------------------------------------------------------------
// Kernel 1: inp = f_ini @ W_i^T (bf16 MFMA); store inp bf16 + msg=relu bf16
// ---------------------------------------------------------------------------
__global__ __launch_bounds__(256, 3) void k_wi(const float* __restrict__ fini,
                                               const ushort* __restrict__ Wi_b,
                                               ushort* __restrict__ inp_b,
                                               ushort* __restrict__ msg) {
    __shared__ ushort At[128 * LDA];
    __shared__ ushort Bt[128 * LDA];
    const int tid = threadIdx.x;
    const int row0 = blockIdx.x * 128;
    const int wave = tid >> 6, lane = tid & 63;
    const int wr = wave & 1, wc = wave >> 1;
    const int l15 = lane & 15, quad = lane >> 4;
    f32x4 acc[4][4] = {};

    for (int c = 0; c < 3; ++c) {   // K chunks of 64 (147 -> 192 zero-pad)
        // A: from fp32 fini (rows of 147, misaligned -> scalar coalesced loads)
        for (int idx = tid; idx < 128 * 64; idx += 256) {
            int r = idx >> 6, f = idx & 63, ff = c * 64 + f;
            float v = (ff < FD) ? fini[(size_t)(row0 + r) * FD + ff] : 0.f;
            At[r * LDA + f] = f2b(v);
        }
        // B: prepped bf16 weights, 16B loads
        for (int idx = tid; idx < 128 * 8; idx += 256) {
            int h = idx >> 3, g = idx & 7;
            *(uint4*)&Bt[h * LDA + g * 8] =
                *(const uint4*)&Wi_b[h * KWI + c * 64 + g * 8];
        }
        __syncthreads();
        mfma_chunk(At, Bt, wr, wc, l15, quad, acc);
        __syncthreads();
    }
#pragma unroll
    for (int i = 0; i < 4; ++i)
#pragma unroll
        for (int reg = 0; reg < 4; ++reg) {
            int row = row0 + wr * 64 + i * 16 + quad * 4 + reg;
#pragma unroll
            for (int j = 0; j < 4; ++j) {
                int col = wc * 64 + j * 16 + l15;
                float v = acc[i][j][reg];
                inp_b[(size_t)row * Hh + col] = f2b(v);
                msg[(size_t)row * Hh + col]  = f2b(v > 0.f ? v : 0.f);
            }
        }
}

// ---------------------------------------------------------------------------
// Kernel 2 (x2): msgOut = relu(inp + gather_sum(msgIn, mapping) @ W_h^T)
// Gather fused into A staging, vectorized bf16x8; mapping staged in LDS.
// ---------------------------------------------------------------------------
__global__ __launch_bounds__(256, 3) void k_hop(const ushort* __restrict__ msgIn,
                                                const int* __restrict__ mapping,
                                                const ushort* __restrict__ Wh_b,
                                                const ushort* __restrict__ inp_b,
                                                ushort* __restrict__ msgOut) {
    __shared__ ushort At[128 * LDA];
    __shared__ ushort Bt[128 * LDA];
    __shared__ int    map_s[128 * Kk];
    const int tid = threadIdx.x;
    const int row0 = blockIdx.x * 128;          // bond-row base (block = half mol)
    const int bBase = row0 & ~(Ee - 1);         // molecule bond base
    const int wave = tid >> 6, lane = tid & 63;
    const int wr = wave & 1, wc = wave >> 1;
    const int l15 = lane & 15, quad = lane >> 4;
    f32x4 acc[4][4] = {};

    for (int i = tid; i < 128 * Kk; i += 256) map_s[i] = mapping[row0 * Kk + i];
    __syncthreads();

    for (int c = 0; c < 2; ++c) {               // K = 128 -> 2 chunks
        for (int t = tid; t < 128 * 8; t += 256) {
            int r = t >> 3, g = t & 7;
            const int* mp = &map_s[r * Kk];
            float2 s0 = {0.f, 0.f}, s1 = {0.f, 0.f}, s2 = {0.f, 0.f}, s3 = {0.f, 0.f};
#pragma unroll
            for (int k = 0; k < Kk; ++k) {
                const uint4 m8 = *(const uint4*)
                    &msgIn[(size_t)(bBase + mp[k]) * Hh + c * 64 + g * 8];
                float2 a = b2f2(m8.x); s0.x += a.x; s0.y += a.y;
                float2 b = b2f2(m8.y); s1.x += b.x; s1.y += b.y;
                float2 d = b2f2(m8.z); s2.x += d.x; s2.y += d.y;
                float2 e = b2f2(m8.w); s3.x += e.x; s3.y += e.y;
            }
            uint4 o;
            o.x = f2b2(s0.x, s0.y); o.y = f2b2(s1.x, s1.y);
            o.z = f2b2(s2.x, s2.y); o.w = f2b2(s3.x, s3.y);
            *(uint4*)&At[r * LDA + g * 8] = o;
        }
        for (int idx = tid; idx < 128 * 8; idx += 256) {
            int h = idx >> 3, g = idx & 7;
            *(uint4*)&Bt[h * LDA + g * 8] =
                *(const uint4*)&Wh_b[h * Hh + c * 64 + g * 8];
        }
        __syncthreads();
        mfma_chunk(At, Bt, wr, wc, l15, quad, acc);
        __syncthreads();
    }
#pragma unroll
    for (int i = 0; i < 4; ++i)
#pragma unroll
        for (int reg = 0; reg < 4; ++reg) {
            int row = row0 + wr * 64 + i * 16 + quad * 4 + reg;
#pragma unroll
            for (int j = 0; j < 4; ++j) {
                int col = wc * 64 + j * 16 + l15;
                float v = b2f(inp_b[(size_t)row * Hh + col]) + acc[i][j][reg];
                msgOut[(size_t)row * Hh + col] = f2b(v > 0.f ? v : 0.f);
            }
        }
}

// ---------------------------------------------------------------------------
// Kernel 3: readout. cat=[atomf | m2a] (padded 320), relu(cat@Wo^T + bo),
// masked scatter into packed output. Block = one molecule (128 atoms).
// ---------------------------------------------------------------------------
__global__ __launch_bounds__(256, 3) void k_read(const ushort* __restrict__ msg,
                                                 const int* __restrict__ a2ib,
                                                 const ushort* __restrict__ atomf_b,
                                                 const ushort* __restrict__ Wo_b,
                                                 const float* __restrict__ bo,
                                                 const int* __restrict__ mol_lens,
                                                 const int* __restrict__ pfx,
                                                 float* __restrict__ out) {
    __shared__ ushort At[128 * LDA];
    __shared__ ushort Bt[128 * LDA];
    __shared__ int    a2_s[128 * Kk];
    const int tid = threadIdx.x;
    const int b = blockIdx.x;
    const int row0 = b * Aa;                    // atom-row base
    const int bBase = b * Ee;                   // bond base for msg gather
    const int wave = tid >> 6, lane = tid & 63;
    const int wr = wave & 1, wc = wave >> 1;
    const int l15 = lane & 15, quad = lane >> 4;
    f32x4 acc[4][4] = {};

    for (int i = tid; i < 128 * Kk; i += 256) a2_s[i] = a2ib[row0 * Kk + i];
    __syncthreads();

    for (int c = 0; c < 5; ++c) {               // K = 320 -> 5 chunks
        if (c < 3) {                            // atomf region (prepped bf16)
            for (int idx = tid; idx < 128 * 8; idx += 256) {
                int r = idx >> 3, g = idx & 7;
                *(uint4*)&At[r * LDA + g * 8] =
                    *(const uint4*)&atomf_b[(size_t)(row0 + r) * KWI + c * 64 + g * 8];
            }
        } else {                                // m2a gather region
            const int hb = (c - 3) * 64;
            for (int t = tid; t < 128 * 8; t += 256) {
                int r = t >> 3, g = t & 7;
                const int* mp = &a2_s[r * Kk];
                float2 s0 = {0.f, 0.f}, s1 = {0.f, 0.f}, s2 = {0.f, 0.f}, s3 = {0.f, 0.f};
#pragma unroll
                for (int k = 0; k < Kk; ++k) {
                    const uint4 m8 = *(const uint4*)
                        &msg[(size_t)(bBase + mp[k]) * Hh + hb + g * 8];
                    float2 a = b2f2(m8.x); s0.x += a.x; s0.y += a.y;
                    float2 bb = b2f2(m8.y); s1.x += bb.x; s1.y += bb.y;
                    float2 d = b2f2(m8.z); s2.x += d.x; s2.y += d.y;
                    float2 e = b2f2(m8.w); s3.x += e.x; s3.y += e.y;
                }
                uint4 o;
                o.x = f2b2(s0.x, s0.y); o.y = f2b2(s1.x, s1.y);
                o.z = f2b2(s2.x, s2.y); o.w = f2b2(s3.x, s3.y);
                *(uint4*)&At[r * LDA + g * 8] = o;
            }
        }
        for (int idx = tid; idx < 128 * 8; idx += 256) {
            int h = idx >> 3, g = idx & 7;
            *(uint4*)&Bt[h * LDA + g * 8] =
                *(const uint4*)&Wo_b[h * KRD + c * 64 + g * 8];
        }
        __syncthreads();
        mfma_chunk(At, Bt, wr, wc, l15, quad, acc);
        __syncthreads();
    }

    const int len  = mol_lens[b];
    const int base = pfx[b];
#pragma unroll
    for (int i = 0; i < 4; ++i)
#pragma unroll
        for (int reg = 0; reg < 4; ++reg) {
            int a = wr * 64 + i * 16 + quad * 4 + reg;   // atom index in mol
            if (a < len) {
#pragma unroll
                for (int j = 0; j < 4; ++j) {
                    int col = wc * 64 + j * 16 + l15;
                    float v = acc[i][j][reg] + bo[col];
                    out[(size_t)(base + a) * Hh + col] = v > 0.f ? v : 0.f;
                }
            }
        }
}

// ---------------------------------------------------------------------------
__global__ __launch_bounds__(512) void k_scan(const int* __restrict__ ml,
                                              int* __restrict__ pfx) {
    __shared__ int s[512];
    int t = threadIdx.x;
    s[t] = ml[t];
    __syncthreads();
    for (int off = 1; off < 512; off <<= 1) {
        int v = (t >= off) ? s[t - off] : 0;
        __syncthreads();
        s[t] += v;
        __syncthreads();
    }
    pfx[t + 1] = s[t];
    if (t == 0) pfx[0] = 0;
}

__global__ __launch_bounds__(128) void k_cmask(const int* __restrict__ ml,
                                               float* __restrict__ cmask) {
    int b = blockIdx.x, t = threadIdx.x;
    cmask[b * Aa + t] = (t < ml[b]) ? 1.0f : 0.0f;
}

// ---------------------------------------------------------------------------
extern "C" void kernel_launch(void* const* d_in, const int* in_sizes, int n_in,
                              void* d_out, int out_size, void* d_ws, size_t ws_size,
                              hipStream_t stream) {
    const float* atom_feature = (const float*)d_in[0];
    const float* f_ini        = (const float*)d_in[1];
    const int*   a2ib         = (const int*)d_in[2];
    const int*   mapping      = (const int*)d_in[3];
    const int*   mol_lens     = (const int*)d_in[5];
    const float* Wi           = (const float*)d_in[6];
    const float* Wh           = (const float*)d_in[7];
    const float* Wo           = (const float*)d_in[8];
    const float* bo           = (const float*)d_in[9];
    float* out = (float*)d_out;

    // Workspace carve (~126 MB)
    constexpr size_t NMSG = (size_t)Bm * Ee * Hh;   // 16,777,216 elems
    constexpr size_t NATM = (size_t)Bm * Aa * KWI;  // 12,582,912 elems
    ushort* inp_b   = (ushort*)d_ws;
    ushort* msgA    = inp_b + NMSG;
    ushort* msgB    = msgA + NMSG;
    ushort* atomf_b = msgB + NMSG;
    ushort* Wi_b    = atomf_b + NATM;
    ushort* Wh_b    = Wi_b + 128 * KWI;
    ushort* Wo_b    = Wh_b + 128 * Hh;
    int*    pfx     = (int*)(Wo_b + 128 * KRD);

    float* cmask = out + ((size_t)out_size - (size_t)Bm * Aa);

    k_prep_w<<<128, 256, 0, stream>>>(Wi, Wh, Wo, Wi_b, Wh_b, Wo_b);
    k_prep_a<<<Bm * Aa, 192, 0, stream>>>(atom_feature, atomf_b);
    k_scan <<<1, 512, 0, stream>>>(mol_lens, pfx);
    k_cmask<<<Bm, 128, 0, stream>>>(mol_lens, cmask);
    k_wi   <<<(Bm * Ee) / 128, 256, 0, stream>>>(f_ini, Wi_b, inp_b, msgA);
    k_hop  <<<(Bm * Ee) / 128, 256, 0, stream>>>(msgA, mapping, Wh_b, inp_b, msgB);
    k_hop  <<<(Bm * Ee) / 128, 256, 0, stream>>>(msgB, mapping, Wh_b, inp_b, msgA);
    k_read <<<Bm, 256, 0, stream>>>(msgA, a2ib, atomf_b, Wo_b, bo,
                                    mol_lens, pfx, out);
}

// Round 3
// 303.316 us; speedup vs baseline: 2.3873x; 1.1832x over previous
//
#include <hip/hip_runtime.h>
#include <hip/hip_bf16.h>

typedef unsigned int   uint;
typedef unsigned short ushort;
typedef short bf16x8 __attribute__((ext_vector_type(8)));
typedef float f32x4  __attribute__((ext_vector_type(4)));

// Problem constants
constexpr int Bm   = 512;   // molecules
constexpr int Aa   = 128;   // atoms / molecule
constexpr int Ee   = 256;   // directed bonds / molecule
constexpr int Kk   = 6;     // incoming gathered
constexpr int AFD  = 133;
constexpr int FD   = 147;   // 133+14
constexpr int Hh   = 128;
constexpr int CATD = 261;   // 133+128
constexpr int KF   = 152;   // fini_b row stride (147 real + 5 zero), 16B-aligned rows
constexpr int KA   = 144;   // atomf_b row stride (133 real + 11 zero)
constexpr int KWO  = 320;   // Wo_b row stride: [0,133) cols, [133,192) zero, [192,320) m2a cols
constexpr int KWIW = 192;   // Wi_b row stride (147 real + 45 zero)
constexpr int LDA  = 72;    // LDS row stride (bf16): 64 + 8 pad

// ---- bf16 helpers ----------------------------------------------------------
__device__ __forceinline__ ushort f2b(float f) {
    uint u = __float_as_uint(f);
    u += 0x7FFFu + ((u >> 16) & 1u);
    return (ushort)(u >> 16);
}
__device__ __forceinline__ uint f2b2(float x, float y) {
    return (uint)f2b(x) | ((uint)f2b(y) << 16);
}
__device__ __forceinline__ float2 b2f2(uint p) {
    float2 r;
    r.x = __uint_as_float(p << 16);
    r.y = __uint_as_float(p & 0xFFFF0000u);
    return r;
}
__device__ __forceinline__ float b2f(ushort u) {
    return __uint_as_float(((uint)u) << 16);
}
// relu on 2 packed bf16: zero halves with sign bit set
__device__ __forceinline__ uint relu2u(uint u) {
    uint neg  = u & 0x80008000u;
    uint mask = (neg >> 15) * 0xFFFFu;   // 0xFFFF per negative half
    return u & ~mask;
}

// ---------------------------------------------------------------------------
// MFMA core: 128x128 block tile, 4 waves 2x2, each wave 4x4 16x16x32 tiles.
// ---------------------------------------------------------------------------
__device__ __forceinline__ void mfma_chunk(const ushort* At, const ushort* Bt,
                                           int wr, int wc, int l15, int quad,
                                           f32x4 acc[4][4]) {
#pragma unroll
    for (int ks = 0; ks < 2; ++ks) {
        const int ko = ks * 32 + quad * 8;
        bf16x8 af[4], bf[4];
#pragma unroll
        for (int i = 0; i < 4; ++i)
            af[i] = *(const bf16x8*)&At[(wr * 64 + i * 16 + l15) * LDA + ko];
#pragma unroll
        for (int j = 0; j < 4; ++j)
            bf[j] = *(const bf16x8*)&Bt[(wc * 64 + j * 16 + l15) * LDA + ko];
#pragma unroll
        for (int i = 0; i < 4; ++i)
#pragma unroll
            for (int j = 0; j < 4; ++j)
                acc[i][j] = __builtin_amdgcn_mfma_f32_16x16x32_bf16(
                    af[i], bf[j], acc[i][j], 0, 0, 0);
    }
}

// ---------------------------------------------------------------------------
// Prep kernels: stream-convert fp32 -> padded bf16
// ---------------------------------------------------------------------------
__global__ __launch_bounds__(256) void k_prep_f(const float* __restrict__ fini,
                                                ushort* __restrict__ fini_b) {
    const int lane = threadIdx.x & 63;
    const int wg   = blockIdx.x * 4 + (threadIdx.x >> 6);   // global wave id, 4096 total
    for (int row = wg; row < Bm * Ee; row += 4096) {
        const float* src = fini + (size_t)row * FD;
        ushort* dst = fini_b + (size_t)row * KF;
        float v0 = src[lane];
        float v1 = src[64 + lane];
        float v2 = (lane < FD - 128) ? src[128 + lane] : 0.f;
        dst[lane]      = f2b(v0);
        dst[64 + lane] = f2b(v1);
        if (lane < KF - 128) dst[128 + lane] = f2b(v2);
    }
}

__global__ __launch_bounds__(256) void k_prep_a(const float* __restrict__ atomf,
                                                ushort* __restrict__ atomf_b) {
    const int lane = threadIdx.x & 63;
    const int wg   = blockIdx.x * 4 + (threadIdx.x >> 6);   // 2048 waves
    for (int row = wg; row < Bm * Aa; row += 2048) {
        const float* src = atomf + (size_t)row * AFD;
        ushort* dst = atomf_b + (size_t)row * KA;
        float v0 = src[lane];
        float v1 = (lane < AFD - 64) ? src[64 + lane] : 0.f;
        float v2 = (lane < AFD - 128) ? src[128 + lane] : 0.f;
        dst[lane]      = f2b(v0);
        dst[64 + lane] = f2b(v1);
        if (lane < KA - 128) dst[128 + lane] = f2b(v2);
    }
}

__global__ __launch_bounds__(256) void k_prep_w(const float* __restrict__ Wi,
                                                const float* __restrict__ Wh,
                                                const float* __restrict__ Wo,
                                                ushort* __restrict__ Wi_b,
                                                ushort* __restrict__ Wh_b,
                                                ushort* __restrict__ Wo_b) {
    const int h = blockIdx.x, t = threadIdx.x;
    for (int c = t; c < KWIW; c += 256)
        Wi_b[h * KWIW + c] = f2b(c < FD ? Wi[h * FD + c] : 0.f);
    for (int c = t; c < Hh; c += 256)
        Wh_b[h * Hh + c] = f2b(Wh[h * Hh + c]);
    for (int c = t; c < KWO; c += 256) {
        float v = 0.f;
        if (c < AFD)       v = Wo[h * CATD + c];
        else if (c >= 192) v = Wo[h * CATD + AFD + (c - 192)];
        Wo_b[h * KWO + c] = f2b(v);
    }
}

// ---------------------------------------------------------------------------
// Kernel 1: inp = f_ini @ W_i^T  (pre-activation only; consumers relu)
// ---------------------------------------------------------------------------
__global__ __launch_bounds__(256, 4) void k_wi(const ushort* __restrict__ fini_b,
                                               const ushort* __restrict__ Wi_b,
                                               ushort* __restrict__ inp_b) {
    __shared__ ushort At[128 * LDA];
    __shared__ ushort Bt[128 * LDA];
    const int tid = threadIdx.x;
    const int row0 = blockIdx.x * 128;
    const int wave = tid >> 6, lane = tid & 63;
    const int wr = wave & 1, wc = wave >> 1;
    const int l15 = lane & 15, quad = lane >> 4;
    f32x4 acc[4][4] = {};

    for (int c = 0; c < 3; ++c) {   // K chunks of 64 (147 -> padded)
        for (int idx = tid; idx < 128 * 8; idx += 256) {
            int r = idx >> 3, g = idx & 7;
            uint4 v = {0, 0, 0, 0};
            if (c < 2 || g < 3)     // fini_b has 152 real+zero cols
                v = *(const uint4*)&fini_b[(size_t)(row0 + r) * KF + c * 64 + g * 8];
            *(uint4*)&At[r * LDA + g * 8] = v;
        }
        for (int idx = tid; idx < 128 * 8; idx += 256) {
            int h = idx >> 3, g = idx & 7;
            *(uint4*)&Bt[h * LDA + g * 8] =
                *(const uint4*)&Wi_b[h * KWIW + c * 64 + g * 8];
        }
        __syncthreads();
        mfma_chunk(At, Bt, wr, wc, l15, quad, acc);
        __syncthreads();
    }
#pragma unroll
    for (int i = 0; i < 4; ++i)
#pragma unroll
        for (int reg = 0; reg < 4; ++reg) {
            int row = row0 + wr * 64 + i * 16 + quad * 4 + reg;
#pragma unroll
            for (int j = 0; j < 4; ++j) {
                int col = wc * 64 + j * 16 + l15;
                inp_b[(size_t)row * Hh + col] = f2b(acc[i][j][reg]);
            }
        }
}

// ---------------------------------------------------------------------------
// Kernel 2 (x2): hOut = inp + gather_sum(relu(hIn), mapping) @ W_h^T
// (pre-activation stored; relu applied during gather)
// ---------------------------------------------------------------------------
__global__ __launch_bounds__(256, 4) void k_hop(const ushort* __restrict__ hIn,
                                                const int* __restrict__ mapping,
                                                const ushort* __restrict__ Wh_b,
                                                const ushort* __restrict__ inp_b,
                                                ushort* __restrict__ hOut) {
    __shared__ ushort At[128 * LDA];
    __shared__ ushort Bt[128 * LDA];
    __shared__ int    map_s[128 * Kk];
    const int tid = threadIdx.x;
    const int row0 = blockIdx.x * 128;          // bond-row base (block = half mol)
    const int bBase = row0 & ~(Ee - 1);         // molecule bond base
    const int wave = tid >> 6, lane = tid & 63;
    const int wr = wave & 1, wc = wave >> 1;
    const int l15 = lane & 15, quad = lane >> 4;
    f32x4 acc[4][4] = {};

    for (int i = tid; i < 128 * Kk; i += 256) map_s[i] = mapping[row0 * Kk + i];
    __syncthreads();

    for (int c = 0; c < 2; ++c) {               // K = 128 -> 2 chunks
        for (int t = tid; t < 128 * 8; t += 256) {
            int r = t >> 3, g = t & 7;
            const int* mp = &map_s[r * Kk];
            float2 s0 = {0.f, 0.f}, s1 = {0.f, 0.f}, s2 = {0.f, 0.f}, s3 = {0.f, 0.f};
#pragma unroll
            for (int k = 0; k < Kk; ++k) {
                uint4 m8 = *(const uint4*)
                    &hIn[(size_t)(bBase + mp[k]) * Hh + c * 64 + g * 8];
                float2 a = b2f2(relu2u(m8.x)); s0.x += a.x; s0.y += a.y;
                float2 b = b2f2(relu2u(m8.y)); s1.x += b.x; s1.y += b.y;
                float2 d = b2f2(relu2u(m8.z)); s2.x += d.x; s2.y += d.y;
                float2 e = b2f2(relu2u(m8.w)); s3.x += e.x; s3.y += e.y;
            }
            uint4 o;
            o.x = f2b2(s0.x, s0.y); o.y = f2b2(s1.x, s1.y);
            o.z = f2b2(s2.x, s2.y); o.w = f2b2(s3.x, s3.y);
            *(uint4*)&At[r * LDA + g * 8] = o;
        }
        for (int idx = tid; idx < 128 * 8; idx += 256) {
            int h = idx >> 3, g = idx & 7;
            *(uint4*)&Bt[h * LDA + g * 8] =
                *(const uint4*)&Wh_b[h * Hh + c * 64 + g * 8];
        }
        __syncthreads();
        mfma_chunk(At, Bt, wr, wc, l15, quad, acc);
        __syncthreads();
    }
#pragma unroll
    for (int i = 0; i < 4; ++i)
#pragma unroll
        for (int reg = 0; reg < 4; ++reg) {
            int row = row0 + wr * 64 + i * 16 + quad * 4 + reg;
#pragma unroll
            for (int j = 0; j < 4; ++j) {
                int col = wc * 64 + j * 16 + l15;
                float v = b2f(inp_b[(size_t)row * Hh + col]) + acc[i][j][reg];
                hOut[(size_t)row * Hh + col] = f2b(v);
            }
        }
}

// ---------------------------------------------------------------------------
// Kernel 3: readout. cat=[atomf | pad | m2a] (K=320), relu(cat@Wo^T + bo),
// masked scatter into packed output. Block = one molecule.
// ---------------------------------------------------------------------------
__global__ __launch_bounds__(256, 4) void k_read(const ushort* __restrict__ h2,
                                                 const int* __restrict__ a2ib,
                                                 const ushort* __restrict__ atomf_b,
                                                 const ushort* __restrict__ Wo_b,
                                                 const float* __restrict__ bo,
                                                 const int* __restrict__ mol_lens,
                                                 const int* __restrict__ pfx,
                                                 float* __restrict__ out) {
    __shared__ ushort At[128 * LDA];
    __shared__ ushort Bt[128 * LDA];
    __shared__ int    a2_s[128 * Kk];
    const int tid = threadIdx.x;
    const int b = blockIdx.x;
    const int row0 = b * Aa;
    const int bBase = b * Ee;
    const int wave = tid >> 6, lane = tid & 63;
    const int wr = wave & 1, wc = wave >> 1;
    const int l15 = lane & 15, quad = lane >> 4;
    f32x4 acc[4][4] = {};

    for (int i = tid; i < 128 * Kk; i += 256) a2_s[i] = a2ib[row0 * Kk + i];
    __syncthreads();

    for (int c = 0; c < 5; ++c) {               // K = 320 -> 5 chunks
        if (c < 3) {                            // atomf region (stride-144 bf16)
            for (int idx = tid; idx < 128 * 8; idx += 256) {
                int r = idx >> 3, g = idx & 7;
                uint4 v = {0, 0, 0, 0};
                if (c < 2 || g < 2)
                    v = *(const uint4*)&atomf_b[(size_t)(row0 + r) * KA + c * 64 + g * 8];
                *(uint4*)&At[r * LDA + g * 8] = v;
            }
        } else {                                // m2a gather region (relu on the fly)
            const int hb = (c - 3) * 64;
            for (int t = tid; t < 128 * 8; t += 256) {
                int r = t >> 3, g = t & 7;
                const int* mp = &a2_s[r * Kk];
                float2 s0 = {0.f, 0.f}, s1 = {0.f, 0.f}, s2 = {0.f, 0.f}, s3 = {0.f, 0.f};
#pragma unroll
                for (int k = 0; k < Kk; ++k) {
                    uint4 m8 = *(const uint4*)
                        &h2[(size_t)(bBase + mp[k]) * Hh + hb + g * 8];
                    float2 a  = b2f2(relu2u(m8.x)); s0.x += a.x;  s0.y += a.y;
                    float2 bb = b2f2(relu2u(m8.y)); s1.x += bb.x; s1.y += bb.y;
                    float2 d  = b2f2(relu2u(m8.z)); s2.x += d.x;  s2.y += d.y;
                    float2 e  = b2f2(relu2u(m8.w)); s3.x += e.x;  s3.y += e.y;
                }
                uint4 o;
                o.x = f2b2(s0.x, s0.y); o.y = f2b2(s1.x, s1.y);
                o.z = f2b2(s2.x, s2.y); o.w = f2b2(s3.x, s3.y);
                *(uint4*)&At[r * LDA + g * 8] = o;
            }
        }
        for (int idx = tid; idx < 128 * 8; idx += 256) {
            int h = idx >> 3, g = idx & 7;
            *(uint4*)&Bt[h * LDA + g * 8] =
                *(const uint4*)&Wo_b[h * KWO + c * 64 + g * 8];
        }
        __syncthreads();
        mfma_chunk(At, Bt, wr, wc, l15, quad, acc);
        __syncthreads();
    }

    const int len  = mol_lens[b];
    const int base = pfx[b];
#pragma unroll
    for (int i = 0; i < 4; ++i)
#pragma unroll
        for (int reg = 0; reg < 4; ++reg) {
            int a = wr * 64 + i * 16 + quad * 4 + reg;
            if (a < len) {
#pragma unroll
                for (int j = 0; j < 4; ++j) {
                    int col = wc * 64 + j * 16 + l15;
                    float v = acc[i][j][reg] + bo[col];
                    out[(size_t)(base + a) * Hh + col] = v > 0.f ? v : 0.f;
                }
            }
        }
}

// ---------------------------------------------------------------------------
__global__ __launch_bounds__(512) void k_scan(const int* __restrict__ ml,
                                              int* __restrict__ pfx) {
    __shared__ int s[512];
    int t = threadIdx.x;
    s[t] = ml[t];
    __syncthreads();
    for (int off = 1; off < 512; off <<= 1) {
        int v = (t >= off) ? s[t - off] : 0;
        __syncthreads();
        s[t] += v;
        __syncthreads();
    }
    pfx[t + 1] = s[t];
    if (t == 0) pfx[0] = 0;
}

__global__ __launch_bounds__(128) void k_cmask(const int* __restrict__ ml,
                                               float* __restrict__ cmask) {
    int b = blockIdx.x, t = threadIdx.x;
    cmask[b * Aa + t] = (t < ml[b]) ? 1.0f : 0.0f;
}

// ---------------------------------------------------------------------------
extern "C" void kernel_launch(void* const* d_in, const int* in_sizes, int n_in,
                              void* d_out, int out_size, void* d_ws, size_t ws_size,
                              hipStream_t stream) {
    const float* atom_feature = (const float*)d_in[0];
    const float* f_ini        = (const float*)d_in[1];
    const int*   a2ib         = (const int*)d_in[2];
    const int*   mapping      = (const int*)d_in[3];
    const int*   mol_lens     = (const int*)d_in[5];
    const float* Wi           = (const float*)d_in[6];
    const float* Wh           = (const float*)d_in[7];
    const float* Wo           = (const float*)d_in[8];
    const float* bo           = (const float*)d_in[9];
    float* out = (float*)d_out;

    // Workspace carve (== round-2's proven 126.0 MB footprint)
    constexpr size_t NMSG  = (size_t)Bm * Ee * Hh;   // 16,777,216
    constexpr size_t NFINI = (size_t)Bm * Ee * KF;   // 19,922,944
    constexpr size_t NATM  = (size_t)Bm * Aa * KA;   //  9,437,184
    ushort* fini_b  = (ushort*)d_ws;
    ushort* h2      = fini_b;                        // aliases fini_b (dead after k_wi)
    ushort* inp_b   = fini_b + NFINI;
    ushort* h1      = inp_b + NMSG;
    ushort* atomf_b = h1 + NMSG;
    ushort* Wi_b    = atomf_b + NATM;
    ushort* Wh_b    = Wi_b + 128 * KWIW;
    ushort* Wo_b    = Wh_b + 128 * Hh;
    int*    pfx     = (int*)(Wo_b + 128 * KWO);

    float* cmask = out + ((size_t)out_size - (size_t)Bm * Aa);

    k_prep_w<<<128, 256, 0, stream>>>(Wi, Wh, Wo, Wi_b, Wh_b, Wo_b);
    k_prep_f<<<1024, 256, 0, stream>>>(f_ini, fini_b);
    k_prep_a<<<512, 256, 0, stream>>>(atom_feature, atomf_b);
    k_scan <<<1, 512, 0, stream>>>(mol_lens, pfx);
    k_cmask<<<Bm, 128, 0, stream>>>(mol_lens, cmask);
    k_wi   <<<(Bm * Ee) / 128, 256, 0, stream>>>(fini_b, Wi_b, inp_b);
    k_hop  <<<(Bm * Ee) / 128, 256, 0, stream>>>(inp_b, mapping, Wh_b, inp_b, h1);
    k_hop  <<<(Bm * Ee) / 128, 256, 0, stream>>>(h1, mapping, Wh_b, inp_b, h2);
    k_read <<<Bm, 256, 0, stream>>>(h2, a2ib, atomf_b, Wo_b, bo,
                                    mol_lens, pfx, out);
}